// Round 6
// baseline (1242.675 us; speedup 1.0000x reference)
//
#include <hip/hip_runtime.h>
#include <cstdint>
#include <cstddef>

constexpr int S = 8192;
constexpr int H = 4096;
constexpr int E = 64;
constexpr int CAP = 256;           // ceil(8192*2/64) = 256
constexpr int KSPLIT = 8;
constexpr int KCHUNK = H / KSPLIT; // 512
constexpr int BK = 32;
constexpr int BM = 256;
constexpr long long SEC = (long long)S * E * CAP; // 134217728
constexpr int GEMM_BLOCKS = (S / BM) * KSPLIT;    // 256
constexpr int FILL_BLOCKS = 2048;

// native clang vector: __builtin_nontemporal_store requires a native
// int/float/pointer/vector type, NOT HIP_vector_type<float,4> (R5 fix).
typedef float floatx4 __attribute__((ext_vector_type(4)));

// ---------------------------------------------------------------------------
// K1 (R4 fusion): fp32 router GEMM + output zero-fill in ONE dispatch.
// Blocks [0,256): 8x8/thread GEMM (bx = b&31 -> M-tile, by = b>>5 -> K-split).
// Blocks [256,2304): floatx4 nontemporal grid-stride zero of the 1.07 GB
// output. No barriers couple the roles; GEMM blocks dispatch first (1/CU),
// fill blocks cycle through the remaining LDS-capped slots, so the ~50 us of
// GEMM compute hides under the ~175 us fill BW window (serial cost was 223).
// fp32 GEMM is mandatory: top-2 ordering feeds an order-dependent cumsum —
// any rounding-induced rank flip cascades into wrong slots (absmax 1.0).
// Block 0 also zeroes the sumg/cnt1 accumulators.
// ---------------------------------------------------------------------------
__global__ __launch_bounds__(256)
void k_gemm_fill(const float* __restrict__ A, const float* __restrict__ W,
                 float* __restrict__ part, float* __restrict__ sumg,
                 int* __restrict__ cnt1, float* __restrict__ out) {
    __shared__ float As[BK][BM + 4];   // 32 x 260 floats = 33.3 KB
    __shared__ float Bs[BK][E + 4];    // 32 x 68  floats =  8.7 KB
    const int tid = threadIdx.x;
    const int b = blockIdx.x;

    if (b >= GEMM_BLOCKS) {            // ---- fill role (block-uniform branch)
        const int fid = b - GEMM_BLOCKS;
        const floatx4 z = {0.f, 0.f, 0.f, 0.f};
        floatx4* o4 = (floatx4*)out;               // [0, 2*SEC) floats
        const size_t n4 = (size_t)SEC / 2;         // 2*SEC/4 float4s
        for (size_t i = (size_t)fid * 256 + tid; i < n4;
             i += (size_t)FILL_BLOCKS * 256)
            __builtin_nontemporal_store(z, &o4[i]);
        if (fid == 0 && tid == 0) out[2 * SEC] = 0.f;  // odd tail element
        return;
    }

    // ---- GEMM role
    if (b == 0) {
        if (tid < 64) sumg[tid] = 0.f;
        else if (tid < 128) cnt1[tid - 64] = 0;
    }
    const int bx = b & 31;             // 0..31  M-tile
    const int by = b >> 5;             // 0..7   K-split
    const int m0 = bx * BM;
    const int kbase = by * KCHUNK;
    const int lr = tid >> 3;           // 0..31
    const int lc = (tid & 7) << 2;     // 0,4,..,28
    const int ty = tid >> 3;           // 0..31 -> 8 rows each (256 rows)
    const int tx = tid & 7;            // 0..7  -> 8 cols each (64 cols)

    float acc[8][8];
#pragma unroll
    for (int i = 0; i < 8; ++i)
#pragma unroll
        for (int j = 0; j < 8; ++j) acc[i][j] = 0.f;

    for (int kc = 0; kc < KCHUNK; kc += BK) {
        // A tile: 256 rows x 32 cols, 8 passes of 32 rows; 8 float4/thread.
        const float* ap = A + (size_t)(m0 + lr) * H + (kbase + kc + lc);
        float4 av[8];
#pragma unroll
        for (int j = 0; j < 8; ++j)
            av[j] = *(const float4*)(ap + (size_t)(32 * j) * H);
        // B tile: 64 rows x 32 cols; 2 float4/thread.
        const float* bp = W + (size_t)lr * H + (kbase + kc + lc);
        const float4 bv0 = *(const float4*)bp;
        const float4 bv1 = *(const float4*)(bp + (size_t)32 * H);
        __syncthreads();
#pragma unroll
        for (int j = 0; j < 8; ++j) {
            As[lc + 0][lr + 32 * j] = av[j].x;
            As[lc + 1][lr + 32 * j] = av[j].y;
            As[lc + 2][lr + 32 * j] = av[j].z;
            As[lc + 3][lr + 32 * j] = av[j].w;
        }
        Bs[lc + 0][lr] = bv0.x; Bs[lc + 1][lr] = bv0.y;
        Bs[lc + 2][lr] = bv0.z; Bs[lc + 3][lr] = bv0.w;
        Bs[lc + 0][lr + 32] = bv1.x; Bs[lc + 1][lr + 32] = bv1.y;
        Bs[lc + 2][lr + 32] = bv1.z; Bs[lc + 3][lr + 32] = bv1.w;
        __syncthreads();
#pragma unroll
        for (int kk = 0; kk < BK; ++kk) {
            const float4 a0 = *(const float4*)&As[kk][ty * 8];
            const float4 a1 = *(const float4*)&As[kk][ty * 8 + 4];
            const float4 b0 = *(const float4*)&Bs[kk][tx * 8];
            const float4 b1 = *(const float4*)&Bs[kk][tx * 8 + 4];
            const float a[8] = {a0.x, a0.y, a0.z, a0.w, a1.x, a1.y, a1.z, a1.w};
            const float bb[8] = {b0.x, b0.y, b0.z, b0.w, b1.x, b1.y, b1.z, b1.w};
#pragma unroll
            for (int i = 0; i < 8; ++i)
#pragma unroll
                for (int j = 0; j < 8; ++j)
                    acc[i][j] = fmaf(a[i], bb[j], acc[i][j]);
        }
    }
    float* P = part + (size_t)by * S * E;
#pragma unroll
    for (int i = 0; i < 8; ++i) {
        const size_t row = (size_t)(m0 + ty * 8 + i);
        float4 v0 = make_float4(acc[i][0], acc[i][1], acc[i][2], acc[i][3]);
        float4 v1 = make_float4(acc[i][4], acc[i][5], acc[i][6], acc[i][7]);
        *(float4*)&P[row * E + tx * 8] = v0;
        *(float4*)&P[row * E + tx * 8 + 4] = v1;
    }
}

// ---------------------------------------------------------------------------
// K2: per-token softmax + top-2 (lane = expert). Deterministic KSPLIT reduce.
// ---------------------------------------------------------------------------
__global__ __launch_bounds__(256)
void k_router(const float* __restrict__ part, int* __restrict__ e1a,
              int* __restrict__ e2a, float* __restrict__ g1a,
              float* __restrict__ g2a, float* __restrict__ sumg,
              int* __restrict__ cnt1) {
    const int lane = threadIdx.x & 63;
    const int gw = blockIdx.x * 4 + (threadIdx.x >> 6);
    float lsum = 0.f;
    int lcnt = 0;
    for (int s = gw; s < S; s += 256) {
        const float* p = part + (size_t)s * E + lane;
        float l = 0.f;
#pragma unroll
        for (int j = 0; j < KSPLIT; ++j)   // fixed order: deterministic
            l += p[(size_t)j * S * E];
        float m = l;
#pragma unroll
        for (int o = 32; o; o >>= 1) m = fmaxf(m, __shfl_xor(m, o));
        const float ex = __expf(l - m);
        float Z = ex;
#pragma unroll
        for (int o = 32; o; o >>= 1) Z += __shfl_xor(Z, o);
        const float g = ex / Z;
        lsum += g;
        float v1 = g; int i1 = lane;
#pragma unroll
        for (int o = 32; o; o >>= 1) {
            const float ov = __shfl_xor(v1, o);
            const int oi = __shfl_xor(i1, o);
            if (ov > v1 || (ov == v1 && oi < i1)) { v1 = ov; i1 = oi; }
        }
        float v2 = (lane == i1) ? -1.f : g; int i2 = lane;
#pragma unroll
        for (int o = 32; o; o >>= 1) {
            const float ov = __shfl_xor(v2, o);
            const int oi = __shfl_xor(i2, o);
            if (ov > v2 || (ov == v2 && oi < i2)) { v2 = ov; i2 = oi; }
        }
        if (i1 == lane) lcnt++;
        if (lane == 0) {
            e1a[s] = i1; e2a[s] = i2; g1a[s] = v1; g2a[s] = v2;
        }
    }
    atomicAdd(&sumg[lane], lsum);
    atomicAdd(&cnt1[lane], lcnt);
}

// ---------------------------------------------------------------------------
// K3 v2 (R2, verified R4: -30 us): ordered slot assignment, 4 waves/block,
// fused mask1+mask2 scan, cross-wave LDS prefix, next-chunk prefetch.
// Rank order (s-ordered, stable intra-ballot) identical to reference cumsum.
// slot2's "+ sum(mask1)" offset deferred to K4 via tot1[e].
// ---------------------------------------------------------------------------
__global__ __launch_bounds__(256)
void k_assign(const int* __restrict__ e1a, const int* __restrict__ e2a,
              int* __restrict__ slot1a, int* __restrict__ slot2a,
              int* __restrict__ tot1) {
    const int e = blockIdx.x;
    const int tid = threadIdx.x;
    const int lane = tid & 63;
    const int w = tid >> 6;                 // wave 0..3
    __shared__ int c1[4], c2[4];
    const unsigned long long below = (1ull << lane) - 1ull;
    int cnt1 = 0, cnt2 = 0;                 // block-wide running totals
    int v1 = e1a[tid], v2 = e2a[tid];       // prefetched chunk 0
    for (int c = 0; c < S; c += 256) {
        const int s = c + tid;
        const int cur1 = v1, cur2 = v2;
        if (c + 256 < S) {                  // prefetch next chunk early
            v1 = e1a[s + 256];
            v2 = e2a[s + 256];
        }
        const bool m1 = (cur1 == e);
        const bool m2 = (cur2 == e);
        const unsigned long long b1 = __ballot(m1);
        const unsigned long long b2 = __ballot(m2);
        if (lane == 0) { c1[w] = __popcll(b1); c2[w] = __popcll(b2); }
        __syncthreads();
        int pre1 = 0, pre2 = 0, t1 = 0, t2 = 0;
#pragma unroll
        for (int i = 0; i < 4; ++i) {
            const int x1 = c1[i], x2 = c2[i];
            if (i < w) { pre1 += x1; pre2 += x2; }
            t1 += x1; t2 += x2;
        }
        if (m1) {
            const int r = cnt1 + pre1 + __popcll(b1 & below);
            slot1a[s] = (r < CAP) ? r : -1;
        }
        if (m2) {
            // raw rank within mask2; final rank = tot1[e] + raw (checked in K4)
            slot2a[s] = cnt2 + pre2 + __popcll(b2 & below);
        }
        cnt1 += t1; cnt2 += t2;
        __syncthreads();                    // c1/c2 reused next iteration
    }
    if (tid == 0) tot1[e] = cnt1;           // full (uncapped) mask1 count
}

// ---------------------------------------------------------------------------
// K4: scatter <=2 nonzeros per token (post-drop denom, per reference) into
// the pre-zeroed output + l_aux in block 0's first wave.
// slot2 capacity check done here: rank2 = tot1[e2] + raw2 (reference's
// loc2 = cumsum(mask2)-1 + sum(mask1)).
// ---------------------------------------------------------------------------
__global__ __launch_bounds__(256)
void k_scatter(const int* __restrict__ e1a, const int* __restrict__ e2a,
               const float* __restrict__ g1a, const float* __restrict__ g2a,
               const int* __restrict__ slot1a, const int* __restrict__ slot2a,
               const int* __restrict__ tot1, const float* __restrict__ sumg,
               const int* __restrict__ cnt1, float* __restrict__ out) {
    const int s = blockIdx.x * 256 + threadIdx.x;
    float* comb = out + 1;
    float* mask = out + 1 + (size_t)SEC;
    const int e2 = e2a[s];
    const int sl1 = slot1a[s];
    const int r2 = slot2a[s] + tot1[e2];    // final mask2 rank
    const bool ok2 = (r2 < CAP);
    const float w1 = (sl1 >= 0) ? g1a[s] : 0.f;
    const float w2 = ok2 ? g2a[s] : 0.f;
    const float denom = fmaxf(w1 + w2, 1.1920928955078125e-07f); // FLT_EPSILON
    if (sl1 >= 0) {
        const size_t off = ((size_t)s * E + e1a[s]) * CAP + sl1;
        comb[off] = w1 / denom;
        mask[off] = 1.f;
    }
    if (ok2) {
        const size_t off = ((size_t)s * E + e2) * CAP + r2;
        comb[off] = w2 / denom;
        mask[off] = 1.f;
    }
    if (blockIdx.x == 0 && threadIdx.x < 64) {
        const int lane = threadIdx.x;
        float v = sumg[lane] * (float)cnt1[lane];
#pragma unroll
        for (int o = 32; o; o >>= 1) v += __shfl_xor(v, o);
        if (lane == 0) out[0] = v * (float)E / ((float)S * (float)S);
    }
}

extern "C" void kernel_launch(void* const* d_in, const int* in_sizes, int n_in,
                              void* d_out, int out_size, void* d_ws,
                              size_t ws_size, hipStream_t stream) {
    const float* A = (const float*)d_in[0];   // gate_input [S,H] fp32
    const float* W = (const float*)d_in[1];   // gate_weight [E,H] fp32
    float* out = (float*)d_out;

    char* ws = (char*)d_ws;
    float* part = (float*)ws;                                   // 16.8 MB
    size_t off = (size_t)KSPLIT * S * E * sizeof(float);
    int* e1a = (int*)(ws + off);      off += (size_t)S * 4;
    int* e2a = (int*)(ws + off);      off += (size_t)S * 4;
    float* g1a = (float*)(ws + off);  off += (size_t)S * 4;
    float* g2a = (float*)(ws + off);  off += (size_t)S * 4;
    int* slot1a = (int*)(ws + off);   off += (size_t)S * 4;
    int* slot2a = (int*)(ws + off);   off += (size_t)S * 4;
    float* sumg = (float*)(ws + off); off += (size_t)E * 4;
    int* cnt1 = (int*)(ws + off);     off += (size_t)E * 4;
    int* tot1 = (int*)(ws + off);     off += (size_t)E * 4;

    // Budget (R4-verified): ~690 us harness ws re-poison + ~170 us harness
    // output poison are fixed. Our controllable stack: out-zero 173 + gemm 50
    // + router/assign/scatter ~30. R4 fusion: the out-zero is folded into the
    // GEMM dispatch (grid-partitioned roles, no shared barriers) so GEMM
    // compute hides under the fill's BW window.
    k_gemm_fill<<<GEMM_BLOCKS + FILL_BLOCKS, 256, 0, stream>>>(
        A, W, part, sumg, cnt1, out);
    k_router<<<64, 256, 0, stream>>>(part, e1a, e2a, g1a, g2a, sumg, cnt1);
    k_assign<<<E, 256, 0, stream>>>(e1a, e2a, slot1a, slot2a, tot1);
    k_scatter<<<S / 256, 256, 0, stream>>>(e1a, e2a, g1a, g2a, slot1a, slot2a,
                                           tot1, sumg, cnt1, out);
}

// Round 8
// 1219.183 us; speedup vs baseline: 1.0193x; 1.0193x over previous
//
#include <hip/hip_runtime.h>
#include <cstdint>
#include <cstddef>

constexpr int S = 8192;
constexpr int H = 4096;
constexpr int E = 64;
constexpr int CAP = 256;           // ceil(8192*2/64) = 256
constexpr int KSPLIT = 8;
constexpr int KCHUNK = H / KSPLIT; // 512
constexpr int BK = 32;
constexpr int BM = 256;
constexpr long long SEC = (long long)S * E * CAP; // 134217728

// ---------------------------------------------------------------------------
// R7: resubmit of the R4-verified best (1224.0 us, absmax 0) -- R7's
// "container failed twice" is an infra flake (same source passed at R4;
// same flake signature as R3, which resolved on unchanged resubmission).
// R6 verdict: grid-partitioned GEMM+fill fusion REGRESSED (+19 us). Fill-role
// blocks inherit the 42KB static LDS (3 blocks/CU cap) and hand fills are
// ~20-43 us slower than rocclr's tuned fill; overlap gain (<50 us of GEMM)
// lost to that. Budget (R4/R6-verified): ~690 us harness ws poison (appears
// even with NO memset of ours -- R6 proof) + ~170 us output restore + ~100 us
// small resets are fixed. Controllable: 173 us mandatory out-zero (at
// 6.2 TB/s fill ceiling) + ~50 us GEMM (27 us fp32-vector floor) + ~30 rest.
// ---------------------------------------------------------------------------

// ---------------------------------------------------------------------------
// K1: fp32 router GEMM  logits[s,e] = sum_k A[s,k] * W[e,k]
// 8x8/thread, BM=256, grid (32, KSPLIT=8). FMA-bound. fp32 is mandatory:
// top-2 ordering feeds an order-dependent cumsum — any rounding-induced rank
// flip cascades into wrong slots (absmax 1.0).
// Block (0,0) also zeroes the sumg/cnt1 accumulators (saves a dispatch).
// ---------------------------------------------------------------------------
__global__ __launch_bounds__(256)
void k_gemm(const float* __restrict__ A, const float* __restrict__ W,
            float* __restrict__ part, float* __restrict__ sumg,
            int* __restrict__ cnt1) {
    __shared__ float As[BK][BM + 4];   // 32 x 260 floats = 33.3 KB
    __shared__ float Bs[BK][E + 4];    // 32 x 68  floats =  8.7 KB
    const int tid = threadIdx.x;
    if (blockIdx.x == 0 && blockIdx.y == 0) {
        if (tid < 64) sumg[tid] = 0.f;
        else if (tid < 128) cnt1[tid - 64] = 0;
    }
    const int m0 = blockIdx.x * BM;
    const int kbase = blockIdx.y * KCHUNK;
    const int lr = tid >> 3;           // 0..31
    const int lc = (tid & 7) << 2;     // 0,4,..,28
    const int ty = tid >> 3;           // 0..31 -> 8 rows each (256 rows)
    const int tx = tid & 7;            // 0..7  -> 8 cols each (64 cols)

    float acc[8][8];
#pragma unroll
    for (int i = 0; i < 8; ++i)
#pragma unroll
        for (int j = 0; j < 8; ++j) acc[i][j] = 0.f;

    for (int kc = 0; kc < KCHUNK; kc += BK) {
        // A tile: 256 rows x 32 cols, 8 passes of 32 rows; 8 float4/thread.
        const float* ap = A + (size_t)(m0 + lr) * H + (kbase + kc + lc);
        float4 av[8];
#pragma unroll
        for (int j = 0; j < 8; ++j)
            av[j] = *(const float4*)(ap + (size_t)(32 * j) * H);
        // B tile: 64 rows x 32 cols; 2 float4/thread.
        const float* bp = W + (size_t)lr * H + (kbase + kc + lc);
        const float4 bv0 = *(const float4*)bp;
        const float4 bv1 = *(const float4*)(bp + (size_t)32 * H);
        __syncthreads();
#pragma unroll
        for (int j = 0; j < 8; ++j) {
            As[lc + 0][lr + 32 * j] = av[j].x;
            As[lc + 1][lr + 32 * j] = av[j].y;
            As[lc + 2][lr + 32 * j] = av[j].z;
            As[lc + 3][lr + 32 * j] = av[j].w;
        }
        Bs[lc + 0][lr] = bv0.x; Bs[lc + 1][lr] = bv0.y;
        Bs[lc + 2][lr] = bv0.z; Bs[lc + 3][lr] = bv0.w;
        Bs[lc + 0][lr + 32] = bv1.x; Bs[lc + 1][lr + 32] = bv1.y;
        Bs[lc + 2][lr + 32] = bv1.z; Bs[lc + 3][lr + 32] = bv1.w;
        __syncthreads();
#pragma unroll
        for (int kk = 0; kk < BK; ++kk) {
            const float4 a0 = *(const float4*)&As[kk][ty * 8];
            const float4 a1 = *(const float4*)&As[kk][ty * 8 + 4];
            const float4 b0 = *(const float4*)&Bs[kk][tx * 8];
            const float4 b1 = *(const float4*)&Bs[kk][tx * 8 + 4];
            const float a[8] = {a0.x, a0.y, a0.z, a0.w, a1.x, a1.y, a1.z, a1.w};
            const float b[8] = {b0.x, b0.y, b0.z, b0.w, b1.x, b1.y, b1.z, b1.w};
#pragma unroll
            for (int i = 0; i < 8; ++i)
#pragma unroll
                for (int j = 0; j < 8; ++j)
                    acc[i][j] = fmaf(a[i], b[j], acc[i][j]);
        }
    }
    float* P = part + (size_t)blockIdx.y * S * E;
#pragma unroll
    for (int i = 0; i < 8; ++i) {
        const size_t row = (size_t)(m0 + ty * 8 + i);
        float4 v0 = make_float4(acc[i][0], acc[i][1], acc[i][2], acc[i][3]);
        float4 v1 = make_float4(acc[i][4], acc[i][5], acc[i][6], acc[i][7]);
        *(float4*)&P[row * E + tx * 8] = v0;
        *(float4*)&P[row * E + tx * 8 + 4] = v1;
    }
}

// ---------------------------------------------------------------------------
// K2: per-token softmax + top-2 (lane = expert). Deterministic KSPLIT reduce.
// ---------------------------------------------------------------------------
__global__ __launch_bounds__(256)
void k_router(const float* __restrict__ part, int* __restrict__ e1a,
              int* __restrict__ e2a, float* __restrict__ g1a,
              float* __restrict__ g2a, float* __restrict__ sumg,
              int* __restrict__ cnt1) {
    const int lane = threadIdx.x & 63;
    const int gw = blockIdx.x * 4 + (threadIdx.x >> 6);
    float lsum = 0.f;
    int lcnt = 0;
    for (int s = gw; s < S; s += 256) {
        const float* p = part + (size_t)s * E + lane;
        float l = 0.f;
#pragma unroll
        for (int j = 0; j < KSPLIT; ++j)   // fixed order: deterministic
            l += p[(size_t)j * S * E];
        float m = l;
#pragma unroll
        for (int o = 32; o; o >>= 1) m = fmaxf(m, __shfl_xor(m, o));
        const float ex = __expf(l - m);
        float Z = ex;
#pragma unroll
        for (int o = 32; o; o >>= 1) Z += __shfl_xor(Z, o);
        const float g = ex / Z;
        lsum += g;
        float v1 = g; int i1 = lane;
#pragma unroll
        for (int o = 32; o; o >>= 1) {
            const float ov = __shfl_xor(v1, o);
            const int oi = __shfl_xor(i1, o);
            if (ov > v1 || (ov == v1 && oi < i1)) { v1 = ov; i1 = oi; }
        }
        float v2 = (lane == i1) ? -1.f : g; int i2 = lane;
#pragma unroll
        for (int o = 32; o; o >>= 1) {
            const float ov = __shfl_xor(v2, o);
            const int oi = __shfl_xor(i2, o);
            if (ov > v2 || (ov == v2 && oi < i2)) { v2 = ov; i2 = oi; }
        }
        if (i1 == lane) lcnt++;
        if (lane == 0) {
            e1a[s] = i1; e2a[s] = i2; g1a[s] = v1; g2a[s] = v2;
        }
    }
    atomicAdd(&sumg[lane], lsum);
    atomicAdd(&cnt1[lane], lcnt);
}

// ---------------------------------------------------------------------------
// K3 v2 (R2, verified R4: -30 us): ordered slot assignment, 4 waves/block,
// fused mask1+mask2 scan, cross-wave LDS prefix, next-chunk prefetch.
// Rank order (s-ordered, stable intra-ballot) identical to reference cumsum.
// slot2's "+ sum(mask1)" offset deferred to K4 via tot1[e].
// ---------------------------------------------------------------------------
__global__ __launch_bounds__(256)
void k_assign(const int* __restrict__ e1a, const int* __restrict__ e2a,
              int* __restrict__ slot1a, int* __restrict__ slot2a,
              int* __restrict__ tot1) {
    const int e = blockIdx.x;
    const int tid = threadIdx.x;
    const int lane = tid & 63;
    const int w = tid >> 6;                 // wave 0..3
    __shared__ int c1[4], c2[4];
    const unsigned long long below = (1ull << lane) - 1ull;
    int cnt1 = 0, cnt2 = 0;                 // block-wide running totals
    int v1 = e1a[tid], v2 = e2a[tid];       // prefetched chunk 0
    for (int c = 0; c < S; c += 256) {
        const int s = c + tid;
        const int cur1 = v1, cur2 = v2;
        if (c + 256 < S) {                  // prefetch next chunk early
            v1 = e1a[s + 256];
            v2 = e2a[s + 256];
        }
        const bool m1 = (cur1 == e);
        const bool m2 = (cur2 == e);
        const unsigned long long b1 = __ballot(m1);
        const unsigned long long b2 = __ballot(m2);
        if (lane == 0) { c1[w] = __popcll(b1); c2[w] = __popcll(b2); }
        __syncthreads();
        int pre1 = 0, pre2 = 0, t1 = 0, t2 = 0;
#pragma unroll
        for (int i = 0; i < 4; ++i) {
            const int x1 = c1[i], x2 = c2[i];
            if (i < w) { pre1 += x1; pre2 += x2; }
            t1 += x1; t2 += x2;
        }
        if (m1) {
            const int r = cnt1 + pre1 + __popcll(b1 & below);
            slot1a[s] = (r < CAP) ? r : -1;
        }
        if (m2) {
            // raw rank within mask2; final rank = tot1[e] + raw (checked in K4)
            slot2a[s] = cnt2 + pre2 + __popcll(b2 & below);
        }
        cnt1 += t1; cnt2 += t2;
        __syncthreads();                    // c1/c2 reused next iteration
    }
    if (tid == 0) tot1[e] = cnt1;           // full (uncapped) mask1 count
}

// ---------------------------------------------------------------------------
// K4: scatter <=2 nonzeros per token (post-drop denom, per reference) into
// the pre-zeroed output + l_aux in block 0's first wave.
// slot2 capacity check done here: rank2 = tot1[e2] + raw2 (reference's
// loc2 = cumsum(mask2)-1 + sum(mask1)).
// ---------------------------------------------------------------------------
__global__ __launch_bounds__(256)
void k_scatter(const int* __restrict__ e1a, const int* __restrict__ e2a,
               const float* __restrict__ g1a, const float* __restrict__ g2a,
               const int* __restrict__ slot1a, const int* __restrict__ slot2a,
               const int* __restrict__ tot1, const float* __restrict__ sumg,
               const int* __restrict__ cnt1, float* __restrict__ out) {
    const int s = blockIdx.x * 256 + threadIdx.x;
    float* comb = out + 1;
    float* mask = out + 1 + (size_t)SEC;
    const int e2 = e2a[s];
    const int sl1 = slot1a[s];
    const int r2 = slot2a[s] + tot1[e2];    // final mask2 rank
    const bool ok2 = (r2 < CAP);
    const float w1 = (sl1 >= 0) ? g1a[s] : 0.f;
    const float w2 = ok2 ? g2a[s] : 0.f;
    const float denom = fmaxf(w1 + w2, 1.1920928955078125e-07f); // FLT_EPSILON
    if (sl1 >= 0) {
        const size_t off = ((size_t)s * E + e1a[s]) * CAP + sl1;
        comb[off] = w1 / denom;
        mask[off] = 1.f;
    }
    if (ok2) {
        const size_t off = ((size_t)s * E + e2) * CAP + r2;
        comb[off] = w2 / denom;
        mask[off] = 1.f;
    }
    if (blockIdx.x == 0 && threadIdx.x < 64) {
        const int lane = threadIdx.x;
        float v = sumg[lane] * (float)cnt1[lane];
#pragma unroll
        for (int o = 32; o; o >>= 1) v += __shfl_xor(v, o);
        if (lane == 0) out[0] = v * (float)E / ((float)S * (float)S);
    }
}

extern "C" void kernel_launch(void* const* d_in, const int* in_sizes, int n_in,
                              void* d_out, int out_size, void* d_ws,
                              size_t ws_size, hipStream_t stream) {
    const float* A = (const float*)d_in[0];   // gate_input [S,H] fp32
    const float* W = (const float*)d_in[1];   // gate_weight [E,H] fp32
    float* out = (float*)d_out;

    char* ws = (char*)d_ws;
    float* part = (float*)ws;                                   // 16.8 MB
    size_t off = (size_t)KSPLIT * S * E * sizeof(float);
    int* e1a = (int*)(ws + off);      off += (size_t)S * 4;
    int* e2a = (int*)(ws + off);      off += (size_t)S * 4;
    float* g1a = (float*)(ws + off);  off += (size_t)S * 4;
    float* g2a = (float*)(ws + off);  off += (size_t)S * 4;
    int* slot1a = (int*)(ws + off);   off += (size_t)S * 4;
    int* slot2a = (int*)(ws + off);   off += (size_t)S * 4;
    float* sumg = (float*)(ws + off); off += (size_t)E * 4;
    int* cnt1 = (int*)(ws + off);     off += (size_t)E * 4;
    int* tot1 = (int*)(ws + off);     off += (size_t)E * 4;

    // Mandatory 1.07 GB output zero -- rocclr fill measured 6.2 TB/s (BW
    // floor); every hand-rolled replacement (prev session R2-R4) and the
    // fused-overlap variant (this session R6) lost to it.
    hipMemsetAsync(d_out, 0, sizeof(float) * (size_t)(1 + 2 * SEC), stream);

    k_gemm<<<dim3(S / BM, KSPLIT), 256, 0, stream>>>(A, W, part, sumg, cnt1);
    k_router<<<64, 256, 0, stream>>>(part, e1a, e2a, g1a, g2a, sumg, cnt1);
    k_assign<<<E, 256, 0, stream>>>(e1a, e2a, slot1a, slot2a, tot1);
    k_scatter<<<S / 256, 256, 0, stream>>>(e1a, e2a, g1a, g2a, slot1a, slot2a,
                                           tot1, sumg, cnt1, out);
}